// Round 7
// baseline (608.134 us; speedup 1.0000x reference)
//
#include <hip/hip_runtime.h>
#include <hip/hip_bf16.h>
#include <math.h>

#define B_ 16
#define NT 64
#define LN 256
#define LV 4
#define D_ 256
#define VOCAB_ 32000
#define M_ 128
#define LS 4
#define ECAP 192  // per-(bn,range8) capacity; mean ~131, sigma ~10.7 -> +5.7 sigma

typedef unsigned short ushort_t;
typedef unsigned int uint_t;

__device__ __forceinline__ ushort_t f2bf(float f) {
  uint_t u = __float_as_uint(f);
  uint_t r = u + 0x7FFFu + ((u >> 16) & 1u);
  return (ushort_t)(r >> 16);
}
__device__ __forceinline__ float bflo(uint_t u) {
  return __uint_as_float(u << 16);
}
__device__ __forceinline__ float bfhi(uint_t u) {
  return __uint_as_float(u & 0xFFFF0000u);
}

// ---------------- K_prep: S gather | C0->bf16 | W_ih^T | W_hh^T | TQK | WvT
// | bucketize kb entries by (value-range8, type), zero-padded to x8 ----------
#define NB_S (3 * B_ * M_)  // 6144
#define NB_CONV 2048
#define NB_TR 192   // 768x256 -> 24x8 tiles of 32x32 (per weight)
#define NB_TQK 256
#define NB_WVT 64   // 256x256 -> 8x8 tiles
#define NB_BKT (B_ * NT)  // 1024 bucketing blocks
__global__ __launch_bounds__(256) void k_prep(
    const int* __restrict__ story, const float* __restrict__ C,
    const float* __restrict__ W_ih, const float* __restrict__ W_hh,
    const float* __restrict__ Wq, const float* __restrict__ Wk,
    const float* __restrict__ Wv, const int* __restrict__ kb_values,
    const int* __restrict__ kb_types, float* __restrict__ S,
    ushort_t* __restrict__ C0h, float* __restrict__ W_ihT,
    float* __restrict__ W_hhT, float* __restrict__ TQK,
    float* __restrict__ WvT, int* __restrict__ entries,
    int* __restrict__ counts, int* __restrict__ qctr) {
  __shared__ __align__(16) char praw[7424];
  float* smem = (float*)praw;  // 32*33 floats fit (4224 B)
  int blk = blockIdx.x, tid = threadIdx.x;
  if (blk == 0 && tid < 8) qctr[tid] = 0;  // reset k_rootsg work queues
  if (blk < NB_S) {
    int h = blk / (B_ * M_);
    int bm = blk % (B_ * M_);
    const int* st = story + (size_t)bm * LS;
    const float* Ch = C + (size_t)h * VOCAB_ * D_;
    float s = Ch[(size_t)st[0] * D_ + tid] + Ch[(size_t)st[1] * D_ + tid] +
              Ch[(size_t)st[2] * D_ + tid] + Ch[(size_t)st[3] * D_ + tid];
    S[(size_t)blk * D_ + tid] = s;
  } else if (blk < NB_S + NB_CONV) {
    int n4 = VOCAB_ * D_ / 4;
    for (int i = (blk - NB_S) * 256 + tid; i < n4; i += NB_CONV * 256) {
      float4 f = ((const float4*)C)[i];
      uint2 packed;
      packed.x = (uint_t)f2bf(f.x) | ((uint_t)f2bf(f.y) << 16);
      packed.y = (uint_t)f2bf(f.z) | ((uint_t)f2bf(f.w) << 16);
      ((uint2*)C0h)[i] = packed;
    }
  } else if (blk < NB_S + NB_CONV + 2 * NB_TR) {
    int t = blk - (NB_S + NB_CONV);
    const float* W = W_ih;
    float* WT = W_ihT;
    if (t >= NB_TR) { t -= NB_TR; W = W_hh; WT = W_hhT; }
    const int R = 768;
    int tr = t % (R / 32), tc = t / (R / 32);
    int tx = tid & 31, ty = tid >> 5;
#pragma unroll
    for (int k = 0; k < 4; ++k)
      smem[(ty + 8 * k) * 33 + tx] =
          W[(size_t)(tr * 32 + ty + 8 * k) * D_ + tc * 32 + tx];
    __syncthreads();
#pragma unroll
    for (int k = 0; k < 4; ++k)
      WT[(size_t)(tc * 32 + ty + 8 * k) * R + tr * 32 + tx] =
          smem[tx * 33 + ty + 8 * k];
  } else if (blk < NB_S + NB_CONV + 2 * NB_TR + NB_TQK) {
    // TQK[j,i] = sum_k Wq[k,j] * Wk[k,i]
    int j = blk - (NB_S + NB_CONV + 2 * NB_TR);
    smem[tid] = Wq[(size_t)tid * D_ + j];
    __syncthreads();
    float acc = 0.f;
#pragma unroll 8
    for (int k = 0; k < D_; ++k) acc += smem[k] * Wk[(size_t)k * D_ + tid];
    TQK[(size_t)j * D_ + tid] = acc;
  } else if (blk < NB_S + NB_CONV + 2 * NB_TR + NB_TQK + NB_WVT) {
    // WvT[j,r] = Wv[r,j]
    int t = blk - (NB_S + NB_CONV + 2 * NB_TR + NB_TQK);
    int tr = t & 7, tc = t >> 3;
    int tx = tid & 31, ty = tid >> 5;
#pragma unroll
    for (int k = 0; k < 4; ++k)
      smem[(ty + 8 * k) * 33 + tx] =
          Wv[(size_t)(tr * 32 + ty + 8 * k) * D_ + tc * 32 + tx];
    __syncthreads();
#pragma unroll
    for (int k = 0; k < 4; ++k)
      WvT[(size_t)(tc * 32 + ty + 8 * k) * D_ + tr * 32 + tx] =
          smem[tx * 33 + ty + 8 * k];
  } else {
    // ---- bucketize: counting-sort (value,type) pairs by (range8,type) ------
    int bn = blk - (NB_S + NB_CONV + 2 * NB_TR + NB_TQK + NB_WVT);
    int* sval = (int*)praw;     // 1024 ints (4 KB)
    int* stype = sval + 1024;   //  256 ints (1 KB)
    int* sbin = stype + 256;    //  512 ints (2 KB): histogram->prefix->ctr
    int* srng = sbin + 512;     //    8 ints: range starts
    int* scnt = srng + 8;       //    8 ints: capped counts
    const int* vp = kb_values + (size_t)bn * LN * LV;
    for (int i = tid; i < LN * LV; i += 256) sval[i] = vp[i];
    stype[tid] = kb_types[(size_t)bn * LN + tid];
    sbin[tid] = 0;
    sbin[256 + tid] = 0;
    __syncthreads();
    int ty = stype[tid];
    int vv[4];
#pragma unroll
    for (int j = 0; j < 4; ++j) {
      vv[j] = sval[tid * 4 + j];
      atomicAdd(&sbin[((vv[j] >> 12) << 6) | ty], 1);
    }
    __syncthreads();
    if (tid < 64) {  // wave 0: exclusive prefix over 512 bins
      int run = 0;
#pragma unroll
      for (int c = 0; c < 8; ++c) {
        int x = sbin[c * 64 + tid];
        int orig = x;
        for (int o = 1; o < 64; o <<= 1) {
          int y = __shfl_up(x, o);
          if ((int)tid >= o) x += y;
        }
        sbin[c * 64 + tid] = x - orig + run;  // exclusive global prefix
        run += __shfl(x, 63);                 // chunk total
      }
    }
    __syncthreads();
    if (tid < 8) {
      srng[tid] = sbin[tid << 6];
      int e = (tid == 7) ? (LN * LV) : sbin[(tid + 1) << 6];
      int cv = min(e - sbin[tid << 6], ECAP);
      counts[bn * 8 + tid] = cv;
      scnt[tid] = cv;
    }
    __syncthreads();
#pragma unroll
    for (int j = 0; j < 4; ++j) {
      int v = vv[j];
      int r = v >> 12;
      int pos = atomicAdd(&sbin[(r << 6) | ty], 1) - srng[r];
      if (pos < ECAP)
        entries[(size_t)(bn * 8 + r) * ECAP + pos] = v | (ty << 16);
    }
    __syncthreads();
    // zero-pad each bucket to x8 (value 0 -> C0 row 0 == 0, type 0 ->
    // T_emb row 0 == 0 -> exact zero contribution)
    if (tid < 8) {
      int cv = scnt[tid];
      int cp = (cv + 7) & ~7;
      for (int p = cv; p < cp; ++p)
        entries[(size_t)(bn * 8 + tid) * ECAP + p] = 0;
    }
  }
}

// ---------------- K_rootsg: 8-range XCC-claimed d-split gather + gates ------
// r4's 4 MB slice == whole XCD L2 -> evictions -> L3-latency reads. Now:
// 8 ranges (2 MB slice = half of one XCD's L2, one range per XCD, claimed by
// real XCC_ID with steal fallback) and each wave-task computes ONE d-HALF of
// one bucket (~128 entries, 4 B/lane loads). T_emb d-half in LDS = 32 KB,
// entry stage 6 KB -> 39 KB LDS -> 4 blocks/CU x 8 waves = 32 waves/CU (max).
// Inner loop = r4's proven form: LDS-staged entries (uniform b128 broadcast),
// readfirstlane scalar row bases, unroll 2 x 4 rows in flight, 0 conflicts
// (t2s float2 = 2-way = free).
#define NBG 2048
#define NRANGE 8
#define UNITS_PER_RANGE 256  // 1024 bn x 2 halves / 8 waves
__global__ __launch_bounds__(512, 8) void k_rootsg(
    const int* __restrict__ counts, const int* __restrict__ entries,
    const ushort_t* __restrict__ C0h, const float* __restrict__ T_emb,
    const int* __restrict__ dec, const float* __restrict__ C0,
    const float* __restrict__ hidden, const float* __restrict__ W_ihT,
    const float* __restrict__ W_hhT, const float* __restrict__ TQK,
    const float* __restrict__ b_ih, const float* __restrict__ b_hh,
    float* __restrict__ part, float* __restrict__ gi, float* __restrict__ gh,
    float* __restrict__ tvec, int* __restrict__ qctr) {
  __shared__ __align__(16) char smem_raw[32768 + 6144 + 16];
  int blk = blockIdx.x, tid = threadIdx.x;
  if (blk < NBG) {
    float2* t2s = (float2*)smem_raw;                // [64 types][64] float2
    int* ent_all = (int*)(smem_raw + 32768);        // [8][192]
    int* sunit = (int*)(smem_raw + 32768 + 6144);   // claim broadcast
    if (tid == 0) {
      int xcd = __builtin_amdgcn_s_getreg(6164) & 7;  // hwreg(XCC_ID=20,0,4)
      int unit = -1;
      for (int a = 0; a < NRANGE && unit < 0; ++a) {
        int rr = (xcd + a) & 7;
        int u = atomicAdd(&qctr[rr], 1);
        if (u < UNITS_PER_RANGE) unit = (u << 3) | rr;
      }
      sunit[0] = unit;
    }
    __syncthreads();
    int unit = sunit[0];
    if (unit < 0) return;  // all units already claimed (safety)
    int rr = unit & 7, u = unit >> 3;
    int h = u & 1, grp = u >> 1;  // d-half, tree-group (0..127)
    // stage T_emb d-half h: t2s[ty*64+c] = T_emb[ty][h*128+2c .. +1]
    const float2* Tg = (const float2*)T_emb;
    for (int i = tid; i < 64 * 64; i += 512)
      t2s[i] = Tg[(i >> 6) * 128 + h * 64 + (i & 63)];
    int wid = tid >> 6, lane = tid & 63;
    int bn = grp * 8 + wid;
    int bucket = bn * 8 + rr;
    int cnt = counts[bucket];
    int cntp = (cnt + 7) & ~7;  // buckets zero-padded to x8
    const int* ge = entries + (size_t)bucket * ECAP;
    int* ent = ent_all + wid * ECAP;
    for (int i = lane; i < cntp; i += 64) ent[i] = ge[i];
    __syncthreads();
    const ushort_t* C0hh = C0h + h * 128 + 2 * lane;
    float a0 = 0.f, a1 = 0.f;
#pragma unroll 2
    for (int k = 0; k < cntp; k += 4) {
      int4 e4 = *(const int4*)(ent + k);  // uniform addr -> b128 broadcast
      int ex = __builtin_amdgcn_readfirstlane(e4.x);
      int ey = __builtin_amdgcn_readfirstlane(e4.y);
      int ez = __builtin_amdgcn_readfirstlane(e4.z);
      int ew = __builtin_amdgcn_readfirstlane(e4.w);
      uint_t u0 = *(const uint_t*)(C0hh + ((size_t)(ex & 0xFFFF) << 8));
      uint_t u1 = *(const uint_t*)(C0hh + ((size_t)(ey & 0xFFFF) << 8));
      uint_t u2 = *(const uint_t*)(C0hh + ((size_t)(ez & 0xFFFF) << 8));
      uint_t u3 = *(const uint_t*)(C0hh + ((size_t)(ew & 0xFFFF) << 8));
      float2 t0 = t2s[((ex >> 16) << 6) | lane];
      float2 t1 = t2s[((ey >> 16) << 6) | lane];
      float2 t2 = t2s[((ez >> 16) << 6) | lane];
      float2 t3 = t2s[((ew >> 16) << 6) | lane];
      a0 += t0.x * bflo(u0) + t1.x * bflo(u1) + t2.x * bflo(u2) +
            t3.x * bflo(u3);
      a1 += t0.y * bfhi(u0) + t1.y * bfhi(u1) + t2.y * bfhi(u2) +
            t3.y * bfhi(u3);
    }
    float2 res;
    res.x = a0;
    res.y = a1;
    ((float2*)(part + (size_t)bucket * D_ + h * 128))[lane] = res;
  } else {
    int g = blk - NBG;  // 0..2: gi, 3..5: gh, 6: tvec
    float* xs = (float*)smem_raw;  // [16][64] = 4 KB, chunked over j
    float acc[B_];
    int i = (g < 3 ? g : g - 3) * 256 + tid;  // valid for tid<256
    if (g < 3) {
      float bias = (tid < 256) ? b_ih[i] : 0.f;
#pragma unroll
      for (int b = 0; b < B_; ++b) acc[b] = bias;
      for (int c = 0; c < 4; ++c) {
        __syncthreads();
        for (int idx = tid; idx < B_ * 64; idx += 512) {
          int b = idx >> 6, jj = idx & 63;
          xs[idx] = C0[(size_t)dec[b] * D_ + c * 64 + jj];
        }
        __syncthreads();
        if (tid < 256) {
#pragma unroll 4
          for (int jj = 0; jj < 64; ++jj) {
            float w = W_ihT[(size_t)(c * 64 + jj) * 768 + i];
#pragma unroll
            for (int b = 0; b < B_; ++b) acc[b] += xs[b * 64 + jj] * w;
          }
        }
      }
      if (tid < 256) {
#pragma unroll
        for (int b = 0; b < B_; ++b) gi[(size_t)b * 768 + i] = acc[b];
      }
    } else if (g < 6) {
      float bias = (tid < 256) ? b_hh[i] : 0.f;
#pragma unroll
      for (int b = 0; b < B_; ++b) acc[b] = bias;
      for (int c = 0; c < 4; ++c) {
        __syncthreads();
        for (int idx = tid; idx < B_ * 64; idx += 512) {
          int b = idx >> 6, jj = idx & 63;
          xs[idx] = hidden[b * D_ + c * 64 + jj];
        }
        __syncthreads();
        if (tid < 256) {
#pragma unroll 4
          for (int jj = 0; jj < 64; ++jj) {
            float w = W_hhT[(size_t)(c * 64 + jj) * 768 + i];
#pragma unroll
            for (int b = 0; b < B_; ++b) acc[b] += xs[b * 64 + jj] * w;
          }
        }
      }
      if (tid < 256) {
#pragma unroll
        for (int b = 0; b < B_; ++b) gh[(size_t)b * 768 + i] = acc[b];
      }
    } else {
#pragma unroll
      for (int b = 0; b < B_; ++b) acc[b] = 0.f;
      for (int c = 0; c < 4; ++c) {
        __syncthreads();
        for (int idx = tid; idx < B_ * 64; idx += 512) {
          int b = idx >> 6, jj = idx & 63;
          xs[idx] = hidden[b * D_ + c * 64 + jj];
        }
        __syncthreads();
        if (tid < 256) {
#pragma unroll 4
          for (int jj = 0; jj < 64; ++jj) {
            float w = TQK[(size_t)(c * 64 + jj) * D_ + tid];
#pragma unroll
            for (int b = 0; b < B_; ++b) acc[b] += xs[b * 64 + jj] * w;
          }
        }
      }
      if (tid < 256) {
#pragma unroll
        for (int b = 0; b < B_; ++b) tvec[b * D_ + tid] = acc[b];
      }
    }
  }
}

// ---------------- K_mid: scores + rsum (1024 blocks) + S transpose (1536) ---
__global__ __launch_bounds__(256) void k_mid(
    const float* __restrict__ part, const float* __restrict__ tvec,
    const float* __restrict__ S, float* __restrict__ scores,
    float* __restrict__ ST, float* __restrict__ rsum) {
  int blk = blockIdx.x, tid = threadIdx.x;
  if (blk < 1024) {
    int b = blk >> 6;
    const float* p = part + (size_t)blk * 8 * D_;
    float rv = 0.f;
#pragma unroll
    for (int r = 0; r < 8; ++r) rv += p[r * D_ + tid];
    rsum[(size_t)blk * D_ + tid] = rv;
    float sc = rv * tvec[b * D_ + tid];
    float sm = rv;
    __shared__ float red[8];
    int lane = tid & 63, wave = tid >> 6;
    for (int o = 32; o > 0; o >>= 1) {
      sc += __shfl_xor(sc, o);
      sm += __shfl_xor(sm, o);
    }
    if (lane == 0) { red[wave] = sc; red[4 + wave] = sm; }
    __syncthreads();
    if (tid == 0) {
      float SC = red[0] + red[1] + red[2] + red[3];
      float SM = red[4] + red[5] + red[6] + red[7];
      scores[blk] = (SM == 0.0f) ? SC - 1000000000.0f : SC;
    }
  } else {
    // ST[hb][d][m] = S[hb][m][d]
    int t = blk - 1024;
    int hb = t >> 5;
    int tile = t & 31;
    int tm = tile & 3, td = tile >> 2;
    int tx = tid & 31, ty = tid >> 5;
    __shared__ float sm2[32 * 33];
    const float* Sp = S + (size_t)hb * M_ * D_;
    float* STp = ST + (size_t)hb * D_ * M_;
#pragma unroll
    for (int k = 0; k < 4; ++k)
      sm2[(ty + 8 * k) * 33 + tx] =
          Sp[(size_t)(tm * 32 + ty + 8 * k) * D_ + td * 32 + tx];
    __syncthreads();
#pragma unroll
    for (int k = 0; k < 4; ++k)
      STp[(size_t)(td * 32 + ty + 8 * k) * M_ + tm * 32 + tx] =
          sm2[tx * 33 + ty + 8 * k];
  }
}

// ---------------- K_chain: softmax/rbar/feat/GRU/hops (grid=16) -------------
__global__ __launch_bounds__(256) void k_chain(
    const float* __restrict__ scores, const float* __restrict__ rsum,
    const float* __restrict__ WvT, const float* __restrict__ gi,
    const float* __restrict__ gh, const float* __restrict__ hidden,
    const float* __restrict__ S, const float* __restrict__ ST,
    float* __restrict__ h_new_out, float* __restrict__ cat,
    float* __restrict__ p_ptr) {
  int b = blockIdx.x, tid = threadIdx.x;
  __shared__ float wsh[NT], rs[D_], us[D_], lo[M_], loB[M_], pr[M_];
  if (tid < NT) {
    float s = scores[b * NT + tid];
    float m = s;
    for (int o = 32; o > 0; o >>= 1) m = fmaxf(m, __shfl_xor(m, o));
    float e = expf(s - m);
    float sum = e;
    for (int o = 32; o > 0; o >>= 1) sum += __shfl_xor(sum, o);
    wsh[tid] = e / sum;
  }
  __syncthreads();
  float rb = 0.f;
#pragma unroll 16
  for (int n = 0; n < NT; ++n)
    rb += wsh[n] * rsum[(size_t)(b * NT + n) * D_ + tid];
  rs[tid] = rb;
  __syncthreads();
  float feat = 0.f;
#pragma unroll 16
  for (int j = 0; j < D_; ++j) feat += rs[j] * WvT[(size_t)j * D_ + tid];
  {
    float i_r = gi[(size_t)b * 768 + tid];
    float i_z = gi[(size_t)b * 768 + 256 + tid];
    float i_n = gi[(size_t)b * 768 + 512 + tid];
    float h_r = gh[(size_t)b * 768 + tid];
    float h_z = gh[(size_t)b * 768 + 256 + tid];
    float h_n = gh[(size_t)b * 768 + 512 + tid];
    float h = hidden[b * D_ + tid];
    float r = 1.f / (1.f + expf(-(i_r + h_r)));
    float z = 1.f / (1.f + expf(-(i_z + h_z)));
    float nn = tanhf(i_n + r * h_n);
    float hn = (1.f - z) * nn + z * h;
    h_new_out[b * D_ + tid] = hn;
    float u0 = hn + feat;
    us[tid] = u0;
    cat[b * 512 + tid] = u0;
  }
  __syncthreads();
  for (int h = 0; h < 3; ++h) {
    {
      int m = tid & 127;
      int half = tid >> 7;
      const float* STp = ST + (((size_t)h * B_ + b) * D_ + half * 128) * M_;
      float l = 0.f;
#pragma unroll 16
      for (int d = 0; d < 128; ++d)
        l += us[half * 128 + d] * STp[(size_t)d * M_ + m];
      if (half == 0) lo[m] = l; else loB[m] = l;
    }
    __syncthreads();
    if (h == 2) {
      if (tid < M_) p_ptr[b * M_ + tid] = lo[tid] + loB[tid];
      break;
    }
    if (tid < 64) {
      float l0 = lo[tid] + loB[tid], l1 = lo[tid + 64] + loB[tid + 64];
      float a = fmaxf(l0, l1);
      for (int o = 32; o > 0; o >>= 1) a = fmaxf(a, __shfl_xor(a, o));
      float e0 = expf(l0 - a), e1 = expf(l1 - a);
      float s = e0 + e1;
      for (int o = 32; o > 0; o >>= 1) s += __shfl_xor(s, o);
      pr[tid] = e0 / s;
      pr[tid + 64] = e1 / s;
    }
    __syncthreads();
    {
      const float* Sn = S + (((size_t)(h + 1) * B_ + b) * M_) * D_;
      float o = 0.f;
#pragma unroll 16
      for (int m = 0; m < M_; ++m) o += pr[m] * Sn[(size_t)m * D_ + tid];
      if (h == 0) cat[b * 512 + D_ + tid] = o;
      us[tid] += o;
    }
    __syncthreads();
  }
}

// ---------------- K_pvocab: p_vocab = cat @ W1_w^T + b ----------------------
__global__ __launch_bounds__(256) void k_pvocab(
    const float* __restrict__ cat, const float* __restrict__ W1_w,
    const float* __restrict__ W1_b, float* __restrict__ out) {
  int blk = blockIdx.x, tid = threadIdx.x;
  int row = tid & 63, q = tid >> 6;  // q in 0..3 (k quarter)
  int v = blk * 64 + row;
  __shared__ float cs[B_ * 512];
  __shared__ float ps[3][64][B_];  // quarters 1..3 partials (12 KB)
  for (int i = tid; i < B_ * 512; i += 256) cs[i] = cat[i];
  __syncthreads();
  const float4* wrow = (const float4*)(W1_w + (size_t)v * 512 + q * 128);
  float acc[B_];
#pragma unroll
  for (int b = 0; b < B_; ++b) acc[b] = 0.f;
#pragma unroll 4
  for (int k4 = 0; k4 < 32; ++k4) {
    float4 w = wrow[k4];
#pragma unroll
    for (int b = 0; b < B_; ++b) {
      const float* c = &cs[b * 512 + q * 128 + k4 * 4];
      acc[b] += w.x * c[0] + w.y * c[1] + w.z * c[2] + w.w * c[3];
    }
  }
  if (q > 0) {
#pragma unroll
    for (int b = 0; b < B_; ++b) ps[q - 1][row][b] = acc[b];
  }
  __syncthreads();
  if (q == 0) {
    float bb = W1_b[v];
#pragma unroll
    for (int b = 0; b < B_; ++b)
      out[(size_t)b * VOCAB_ + v] =
          acc[b] + ps[0][row][b] + ps[1][row][b] + ps[2][row][b] + bb;
  }
}

extern "C" void kernel_launch(void* const* d_in, const int* in_sizes, int n_in,
                              void* d_out, int out_size, void* d_ws,
                              size_t ws_size, hipStream_t stream) {
  const int* decoder_input = (const int*)d_in[0];
  const int* story = (const int*)d_in[1];
  const float* hidden = (const float*)d_in[2];
  const int* kb_values = (const int*)d_in[3];
  const int* kb_types = (const int*)d_in[4];
  const float* C = (const float*)d_in[7];
  const float* T_emb = (const float*)d_in[8];
  const float* Wq = (const float*)d_in[9];
  const float* Wk = (const float*)d_in[10];
  const float* Wv = (const float*)d_in[11];
  const float* W1_w = (const float*)d_in[12];
  const float* W1_b = (const float*)d_in[13];
  const float* W_ih = (const float*)d_in[14];
  const float* W_hh = (const float*)d_in[15];
  const float* b_ih = (const float*)d_in[16];
  const float* b_hh = (const float*)d_in[17];

  float* out = (float*)d_out;
  float* p_ptr = out;                          // (16,128)
  float* p_vocab = out + B_ * M_;              // (16,32000)
  float* h_new = out + B_ * M_ + B_ * VOCAB_;  // (16,256)

  // workspace layout (floats). entries aliases into the wtmp tail (dead by
  // k_mid, when ST overwrites); WvT sits past both ST and entries.
  float* ws = (float*)d_ws;
  float* S = ws;                           // 1,572,864
  float* part = S + 3 * B_ * M_ * D_;      // 2,097,152 (B*NT*8ranges*D)
  float* rsum = part + B_ * NT * 8 * D_;   //   262,144
  float* cat = rsum + B_ * NT * D_;        //     8,192
  float* scores = cat + B_ * 512;          //     1,024
  float* gi = scores + B_ * NT;            //    12,288
  float* gh = gi + B_ * 768;               //    12,288
  float* tvec = gh + B_ * 768;             //     4,096
  int* counts = (int*)(tvec + B_ * D_);    //     8,192 ints
  int* qctr = counts + 8192;               //         8 ints (work queues)
  ushort_t* C0h = (ushort_t*)(qctr + 8);   // 8,192,000 ushorts
  float* wtmp = (float*)(C0h + (size_t)VOCAB_ * D_);
  float* W_ihT = wtmp;                        //   196,608
  float* W_hhT = W_ihT + 768 * D_;            //   196,608
  float* TQK = W_hhT + 768 * D_;              //    65,536
  int* entries = (int*)(TQK + D_ * D_);       // 1,572,864 ints (8192*ECAP)
  float* ST = wtmp;                           // alias: 1,572,864 (k_mid+)
  float* WvT = wtmp + (458752 + 1572864);     //    65,536 (past ST & entries)

  hipLaunchKernelGGL(
      k_prep, dim3(NB_S + NB_CONV + 2 * NB_TR + NB_TQK + NB_WVT + NB_BKT),
      dim3(256), 0, stream, story, C, W_ih, W_hh, Wq, Wk, Wv, kb_values,
      kb_types, S, C0h, W_ihT, W_hhT, TQK, WvT, entries, counts, qctr);
  hipLaunchKernelGGL(k_rootsg, dim3(NBG + 7), dim3(512), 0, stream, counts,
                     entries, C0h, T_emb, decoder_input, C, hidden, W_ihT,
                     W_hhT, TQK, b_ih, b_hh, part, gi, gh, tvec, qctr);
  hipLaunchKernelGGL(k_mid, dim3(1024 + 1536), dim3(256), 0, stream, part,
                     tvec, S, scores, ST, rsum);
  hipLaunchKernelGGL(k_chain, dim3(B_), dim3(256), 0, stream, scores, rsum,
                     WvT, gi, gh, hidden, S, ST, h_new, cat, p_ptr);
  hipLaunchKernelGGL(k_pvocab, dim3(VOCAB_ / 64), dim3(256), 0, stream, cat,
                     W1_w, W1_b, p_vocab);
}

// Round 8
// 453.966 us; speedup vs baseline: 1.3396x; 1.3396x over previous
//
#include <hip/hip_runtime.h>
#include <hip/hip_bf16.h>
#include <math.h>

#define B_ 16
#define NT 64
#define LN 256
#define LV 4
#define D_ 256
#define VOCAB_ 32000
#define M_ 128
#define LS 4
#define ECAP 192  // per-(bn,range8) capacity; mean ~131, sigma ~10.7 -> +5.7 sigma

typedef unsigned short ushort_t;
typedef unsigned int uint_t;

__device__ __forceinline__ ushort_t f2bf(float f) {
  uint_t u = __float_as_uint(f);
  uint_t r = u + 0x7FFFu + ((u >> 16) & 1u);
  return (ushort_t)(r >> 16);
}
__device__ __forceinline__ float bflo(uint_t u) {
  return __uint_as_float(u << 16);
}
__device__ __forceinline__ float bfhi(uint_t u) {
  return __uint_as_float(u & 0xFFFF0000u);
}

// ---------------- K_prep: S gather | C0->bf16 | W_ih^T | W_hh^T | TQK | WvT
// | bucketize kb entries by (value-range8, type), zero-padded to x8 ----------
#define NB_S (3 * B_ * M_)  // 6144
#define NB_CONV 2048
#define NB_TR 192   // 768x256 -> 24x8 tiles of 32x32 (per weight)
#define NB_TQK 256
#define NB_WVT 64   // 256x256 -> 8x8 tiles
#define NB_BKT (B_ * NT)  // 1024 bucketing blocks
__global__ __launch_bounds__(256) void k_prep(
    const int* __restrict__ story, const float* __restrict__ C,
    const float* __restrict__ W_ih, const float* __restrict__ W_hh,
    const float* __restrict__ Wq, const float* __restrict__ Wk,
    const float* __restrict__ Wv, const int* __restrict__ kb_values,
    const int* __restrict__ kb_types, float* __restrict__ S,
    ushort_t* __restrict__ C0h, float* __restrict__ W_ihT,
    float* __restrict__ W_hhT, float* __restrict__ TQK,
    float* __restrict__ WvT, int* __restrict__ entries,
    int* __restrict__ counts, int* __restrict__ qctr) {
  __shared__ __align__(16) char praw[7424];
  float* smem = (float*)praw;  // 32*33 floats fit (4224 B)
  int blk = blockIdx.x, tid = threadIdx.x;
  if (blk == 0 && tid < 8) qctr[tid] = 0;  // reset k_rootsg work queues
  if (blk < NB_S) {
    int h = blk / (B_ * M_);
    int bm = blk % (B_ * M_);
    const int* st = story + (size_t)bm * LS;
    const float* Ch = C + (size_t)h * VOCAB_ * D_;
    float s = Ch[(size_t)st[0] * D_ + tid] + Ch[(size_t)st[1] * D_ + tid] +
              Ch[(size_t)st[2] * D_ + tid] + Ch[(size_t)st[3] * D_ + tid];
    S[(size_t)blk * D_ + tid] = s;
  } else if (blk < NB_S + NB_CONV) {
    int n4 = VOCAB_ * D_ / 4;
    for (int i = (blk - NB_S) * 256 + tid; i < n4; i += NB_CONV * 256) {
      float4 f = ((const float4*)C)[i];
      uint2 packed;
      packed.x = (uint_t)f2bf(f.x) | ((uint_t)f2bf(f.y) << 16);
      packed.y = (uint_t)f2bf(f.z) | ((uint_t)f2bf(f.w) << 16);
      ((uint2*)C0h)[i] = packed;
    }
  } else if (blk < NB_S + NB_CONV + 2 * NB_TR) {
    int t = blk - (NB_S + NB_CONV);
    const float* W = W_ih;
    float* WT = W_ihT;
    if (t >= NB_TR) { t -= NB_TR; W = W_hh; WT = W_hhT; }
    const int R = 768;
    int tr = t % (R / 32), tc = t / (R / 32);
    int tx = tid & 31, ty = tid >> 5;
#pragma unroll
    for (int k = 0; k < 4; ++k)
      smem[(ty + 8 * k) * 33 + tx] =
          W[(size_t)(tr * 32 + ty + 8 * k) * D_ + tc * 32 + tx];
    __syncthreads();
#pragma unroll
    for (int k = 0; k < 4; ++k)
      WT[(size_t)(tc * 32 + ty + 8 * k) * R + tr * 32 + tx] =
          smem[tx * 33 + ty + 8 * k];
  } else if (blk < NB_S + NB_CONV + 2 * NB_TR + NB_TQK) {
    // TQK[j,i] = sum_k Wq[k,j] * Wk[k,i]
    int j = blk - (NB_S + NB_CONV + 2 * NB_TR);
    smem[tid] = Wq[(size_t)tid * D_ + j];
    __syncthreads();
    float acc = 0.f;
#pragma unroll 8
    for (int k = 0; k < D_; ++k) acc += smem[k] * Wk[(size_t)k * D_ + tid];
    TQK[(size_t)j * D_ + tid] = acc;
  } else if (blk < NB_S + NB_CONV + 2 * NB_TR + NB_TQK + NB_WVT) {
    // WvT[j,r] = Wv[r,j]
    int t = blk - (NB_S + NB_CONV + 2 * NB_TR + NB_TQK);
    int tr = t & 7, tc = t >> 3;
    int tx = tid & 31, ty = tid >> 5;
#pragma unroll
    for (int k = 0; k < 4; ++k)
      smem[(ty + 8 * k) * 33 + tx] =
          Wv[(size_t)(tr * 32 + ty + 8 * k) * D_ + tc * 32 + tx];
    __syncthreads();
#pragma unroll
    for (int k = 0; k < 4; ++k)
      WvT[(size_t)(tc * 32 + ty + 8 * k) * D_ + tr * 32 + tx] =
          smem[tx * 33 + ty + 8 * k];
  } else {
    // ---- bucketize: counting-sort (value,type) pairs by (range8,type) ------
    int bn = blk - (NB_S + NB_CONV + 2 * NB_TR + NB_TQK + NB_WVT);
    int* sval = (int*)praw;     // 1024 ints (4 KB)
    int* stype = sval + 1024;   //  256 ints (1 KB)
    int* sbin = stype + 256;    //  512 ints (2 KB): histogram->prefix->ctr
    int* srng = sbin + 512;     //    8 ints: range starts
    int* scnt = srng + 8;       //    8 ints: capped counts
    const int* vp = kb_values + (size_t)bn * LN * LV;
    for (int i = tid; i < LN * LV; i += 256) sval[i] = vp[i];
    stype[tid] = kb_types[(size_t)bn * LN + tid];
    sbin[tid] = 0;
    sbin[256 + tid] = 0;
    __syncthreads();
    int ty = stype[tid];
    int vv[4];
#pragma unroll
    for (int j = 0; j < 4; ++j) {
      vv[j] = sval[tid * 4 + j];
      atomicAdd(&sbin[((vv[j] >> 12) << 6) | ty], 1);
    }
    __syncthreads();
    if (tid < 64) {  // wave 0: exclusive prefix over 512 bins
      int run = 0;
#pragma unroll
      for (int c = 0; c < 8; ++c) {
        int x = sbin[c * 64 + tid];
        int orig = x;
        for (int o = 1; o < 64; o <<= 1) {
          int y = __shfl_up(x, o);
          if ((int)tid >= o) x += y;
        }
        sbin[c * 64 + tid] = x - orig + run;  // exclusive global prefix
        run += __shfl(x, 63);                 // chunk total
      }
    }
    __syncthreads();
    if (tid < 8) {
      srng[tid] = sbin[tid << 6];
      int e = (tid == 7) ? (LN * LV) : sbin[(tid + 1) << 6];
      int cv = min(e - sbin[tid << 6], ECAP);
      counts[bn * 8 + tid] = cv;
      scnt[tid] = cv;
    }
    __syncthreads();
#pragma unroll
    for (int j = 0; j < 4; ++j) {
      int v = vv[j];
      int r = v >> 12;
      int pos = atomicAdd(&sbin[(r << 6) | ty], 1) - srng[r];
      if (pos < ECAP)
        entries[(size_t)(bn * 8 + r) * ECAP + pos] = v | (ty << 16);
    }
    __syncthreads();
    // zero-pad each bucket to x8 (value 0 -> C0 row 0 == 0, type 0 ->
    // T_emb row 0 == 0 -> exact zero contribution)
    if (tid < 8) {
      int cv = scnt[tid];
      int cp = (cv + 7) & ~7;
      for (int p = cv; p < cp; ++p)
        entries[(size_t)(bn * 8 + tid) * ECAP + p] = 0;
    }
  }
}

// ---------------- K_rootsg: 8-range XCC-claimed d-split gather + gates ------
// r7 verified the structure (FETCH 12 MB, 0 conflicts, occ 33%) but
// __launch_bounds__(512,8) forced VGPR=32 -> loads fully serialized (311 us;
// same 32-VGPR failure as r5). This round: identical kernel, bound relaxed to
// __launch_bounds__(512) -> ~60 VGPR, 8 independent loads in flight per wave
// (unroll 2 x 4 SGPR-based row loads), LDS 39.4 KB still 4 blocks/CU.
#define NBG 2048
#define NRANGE 8
#define UNITS_PER_RANGE 256  // 1024 bn x 2 halves / 8 waves
__global__ __launch_bounds__(512) void k_rootsg(
    const int* __restrict__ counts, const int* __restrict__ entries,
    const ushort_t* __restrict__ C0h, const float* __restrict__ T_emb,
    const int* __restrict__ dec, const float* __restrict__ C0,
    const float* __restrict__ hidden, const float* __restrict__ W_ihT,
    const float* __restrict__ W_hhT, const float* __restrict__ TQK,
    const float* __restrict__ b_ih, const float* __restrict__ b_hh,
    float* __restrict__ part, float* __restrict__ gi, float* __restrict__ gh,
    float* __restrict__ tvec, int* __restrict__ qctr) {
  __shared__ __align__(16) char smem_raw[32768 + 6144 + 16];
  int blk = blockIdx.x, tid = threadIdx.x;
  if (blk < NBG) {
    float2* t2s = (float2*)smem_raw;                // [64 types][64] float2
    int* ent_all = (int*)(smem_raw + 32768);        // [8][192]
    int* sunit = (int*)(smem_raw + 32768 + 6144);   // claim broadcast
    if (tid == 0) {
      int xcd = __builtin_amdgcn_s_getreg(6164) & 7;  // hwreg(XCC_ID=20,0,4)
      int unit = -1;
      for (int a = 0; a < NRANGE && unit < 0; ++a) {
        int rr = (xcd + a) & 7;
        int u = atomicAdd(&qctr[rr], 1);
        if (u < UNITS_PER_RANGE) unit = (u << 3) | rr;
      }
      sunit[0] = unit;
    }
    __syncthreads();
    int unit = sunit[0];
    if (unit < 0) return;  // all units already claimed (safety)
    int rr = unit & 7, u = unit >> 3;
    int h = u & 1, grp = u >> 1;  // d-half, tree-group (0..127)
    // stage T_emb d-half h: t2s[ty*64+c] = T_emb[ty][h*128+2c .. +1]
    const float2* Tg = (const float2*)T_emb;
    for (int i = tid; i < 64 * 64; i += 512)
      t2s[i] = Tg[(i >> 6) * 128 + h * 64 + (i & 63)];
    int wid = tid >> 6, lane = tid & 63;
    int bn = grp * 8 + wid;
    int bucket = bn * 8 + rr;
    int cnt = counts[bucket];
    int cntp = (cnt + 7) & ~7;  // buckets zero-padded to x8
    const int* ge = entries + (size_t)bucket * ECAP;
    int* ent = ent_all + wid * ECAP;
    for (int i = lane; i < cntp; i += 64) ent[i] = ge[i];
    __syncthreads();
    const ushort_t* C0hh = C0h + h * 128 + 2 * lane;
    float a0 = 0.f, a1 = 0.f;
#pragma unroll 2
    for (int k = 0; k < cntp; k += 4) {
      int4 e4 = *(const int4*)(ent + k);  // uniform addr -> b128 broadcast
      int ex = __builtin_amdgcn_readfirstlane(e4.x);
      int ey = __builtin_amdgcn_readfirstlane(e4.y);
      int ez = __builtin_amdgcn_readfirstlane(e4.z);
      int ew = __builtin_amdgcn_readfirstlane(e4.w);
      uint_t u0 = *(const uint_t*)(C0hh + ((size_t)(ex & 0xFFFF) << 8));
      uint_t u1 = *(const uint_t*)(C0hh + ((size_t)(ey & 0xFFFF) << 8));
      uint_t u2 = *(const uint_t*)(C0hh + ((size_t)(ez & 0xFFFF) << 8));
      uint_t u3 = *(const uint_t*)(C0hh + ((size_t)(ew & 0xFFFF) << 8));
      float2 t0 = t2s[((ex >> 16) << 6) | lane];
      float2 t1 = t2s[((ey >> 16) << 6) | lane];
      float2 t2 = t2s[((ez >> 16) << 6) | lane];
      float2 t3 = t2s[((ew >> 16) << 6) | lane];
      a0 += t0.x * bflo(u0) + t1.x * bflo(u1) + t2.x * bflo(u2) +
            t3.x * bflo(u3);
      a1 += t0.y * bfhi(u0) + t1.y * bfhi(u1) + t2.y * bfhi(u2) +
            t3.y * bfhi(u3);
    }
    float2 res;
    res.x = a0;
    res.y = a1;
    ((float2*)(part + (size_t)bucket * D_ + h * 128))[lane] = res;
  } else {
    int g = blk - NBG;  // 0..2: gi, 3..5: gh, 6: tvec
    float* xs = (float*)smem_raw;  // [16][64] = 4 KB, chunked over j
    float acc[B_];
    int i = (g < 3 ? g : g - 3) * 256 + tid;  // valid for tid<256
    if (g < 3) {
      float bias = (tid < 256) ? b_ih[i] : 0.f;
#pragma unroll
      for (int b = 0; b < B_; ++b) acc[b] = bias;
      for (int c = 0; c < 4; ++c) {
        __syncthreads();
        for (int idx = tid; idx < B_ * 64; idx += 512) {
          int b = idx >> 6, jj = idx & 63;
          xs[idx] = C0[(size_t)dec[b] * D_ + c * 64 + jj];
        }
        __syncthreads();
        if (tid < 256) {
#pragma unroll 4
          for (int jj = 0; jj < 64; ++jj) {
            float w = W_ihT[(size_t)(c * 64 + jj) * 768 + i];
#pragma unroll
            for (int b = 0; b < B_; ++b) acc[b] += xs[b * 64 + jj] * w;
          }
        }
      }
      if (tid < 256) {
#pragma unroll
        for (int b = 0; b < B_; ++b) gi[(size_t)b * 768 + i] = acc[b];
      }
    } else if (g < 6) {
      float bias = (tid < 256) ? b_hh[i] : 0.f;
#pragma unroll
      for (int b = 0; b < B_; ++b) acc[b] = bias;
      for (int c = 0; c < 4; ++c) {
        __syncthreads();
        for (int idx = tid; idx < B_ * 64; idx += 512) {
          int b = idx >> 6, jj = idx & 63;
          xs[idx] = hidden[b * D_ + c * 64 + jj];
        }
        __syncthreads();
        if (tid < 256) {
#pragma unroll 4
          for (int jj = 0; jj < 64; ++jj) {
            float w = W_hhT[(size_t)(c * 64 + jj) * 768 + i];
#pragma unroll
            for (int b = 0; b < B_; ++b) acc[b] += xs[b * 64 + jj] * w;
          }
        }
      }
      if (tid < 256) {
#pragma unroll
        for (int b = 0; b < B_; ++b) gh[(size_t)b * 768 + i] = acc[b];
      }
    } else {
#pragma unroll
      for (int b = 0; b < B_; ++b) acc[b] = 0.f;
      for (int c = 0; c < 4; ++c) {
        __syncthreads();
        for (int idx = tid; idx < B_ * 64; idx += 512) {
          int b = idx >> 6, jj = idx & 63;
          xs[idx] = hidden[b * D_ + c * 64 + jj];
        }
        __syncthreads();
        if (tid < 256) {
#pragma unroll 4
          for (int jj = 0; jj < 64; ++jj) {
            float w = TQK[(size_t)(c * 64 + jj) * D_ + tid];
#pragma unroll
            for (int b = 0; b < B_; ++b) acc[b] += xs[b * 64 + jj] * w;
          }
        }
      }
      if (tid < 256) {
#pragma unroll
        for (int b = 0; b < B_; ++b) tvec[b * D_ + tid] = acc[b];
      }
    }
  }
}

// ---------------- K_mid: scores + rsum (1024 blocks) + S transpose (1536) ---
__global__ __launch_bounds__(256) void k_mid(
    const float* __restrict__ part, const float* __restrict__ tvec,
    const float* __restrict__ S, float* __restrict__ scores,
    float* __restrict__ ST, float* __restrict__ rsum) {
  int blk = blockIdx.x, tid = threadIdx.x;
  if (blk < 1024) {
    int b = blk >> 6;
    const float* p = part + (size_t)blk * 8 * D_;
    float rv = 0.f;
#pragma unroll
    for (int r = 0; r < 8; ++r) rv += p[r * D_ + tid];
    rsum[(size_t)blk * D_ + tid] = rv;
    float sc = rv * tvec[b * D_ + tid];
    float sm = rv;
    __shared__ float red[8];
    int lane = tid & 63, wave = tid >> 6;
    for (int o = 32; o > 0; o >>= 1) {
      sc += __shfl_xor(sc, o);
      sm += __shfl_xor(sm, o);
    }
    if (lane == 0) { red[wave] = sc; red[4 + wave] = sm; }
    __syncthreads();
    if (tid == 0) {
      float SC = red[0] + red[1] + red[2] + red[3];
      float SM = red[4] + red[5] + red[6] + red[7];
      scores[blk] = (SM == 0.0f) ? SC - 1000000000.0f : SC;
    }
  } else {
    // ST[hb][d][m] = S[hb][m][d]
    int t = blk - 1024;
    int hb = t >> 5;
    int tile = t & 31;
    int tm = tile & 3, td = tile >> 2;
    int tx = tid & 31, ty = tid >> 5;
    __shared__ float sm2[32 * 33];
    const float* Sp = S + (size_t)hb * M_ * D_;
    float* STp = ST + (size_t)hb * D_ * M_;
#pragma unroll
    for (int k = 0; k < 4; ++k)
      sm2[(ty + 8 * k) * 33 + tx] =
          Sp[(size_t)(tm * 32 + ty + 8 * k) * D_ + td * 32 + tx];
    __syncthreads();
#pragma unroll
    for (int k = 0; k < 4; ++k)
      STp[(size_t)(td * 32 + ty + 8 * k) * M_ + tm * 32 + tx] =
          sm2[tx * 33 + ty + 8 * k];
  }
}

// ---------------- K_chain: softmax/rbar/feat/GRU/hops (grid=16) -------------
__global__ __launch_bounds__(256) void k_chain(
    const float* __restrict__ scores, const float* __restrict__ rsum,
    const float* __restrict__ WvT, const float* __restrict__ gi,
    const float* __restrict__ gh, const float* __restrict__ hidden,
    const float* __restrict__ S, const float* __restrict__ ST,
    float* __restrict__ h_new_out, float* __restrict__ cat,
    float* __restrict__ p_ptr) {
  int b = blockIdx.x, tid = threadIdx.x;
  __shared__ float wsh[NT], rs[D_], us[D_], lo[M_], loB[M_], pr[M_];
  if (tid < NT) {
    float s = scores[b * NT + tid];
    float m = s;
    for (int o = 32; o > 0; o >>= 1) m = fmaxf(m, __shfl_xor(m, o));
    float e = expf(s - m);
    float sum = e;
    for (int o = 32; o > 0; o >>= 1) sum += __shfl_xor(sum, o);
    wsh[tid] = e / sum;
  }
  __syncthreads();
  float rb = 0.f;
#pragma unroll 16
  for (int n = 0; n < NT; ++n)
    rb += wsh[n] * rsum[(size_t)(b * NT + n) * D_ + tid];
  rs[tid] = rb;
  __syncthreads();
  float feat = 0.f;
#pragma unroll 16
  for (int j = 0; j < D_; ++j) feat += rs[j] * WvT[(size_t)j * D_ + tid];
  {
    float i_r = gi[(size_t)b * 768 + tid];
    float i_z = gi[(size_t)b * 768 + 256 + tid];
    float i_n = gi[(size_t)b * 768 + 512 + tid];
    float h_r = gh[(size_t)b * 768 + tid];
    float h_z = gh[(size_t)b * 768 + 256 + tid];
    float h_n = gh[(size_t)b * 768 + 512 + tid];
    float h = hidden[b * D_ + tid];
    float r = 1.f / (1.f + expf(-(i_r + h_r)));
    float z = 1.f / (1.f + expf(-(i_z + h_z)));
    float nn = tanhf(i_n + r * h_n);
    float hn = (1.f - z) * nn + z * h;
    h_new_out[b * D_ + tid] = hn;
    float u0 = hn + feat;
    us[tid] = u0;
    cat[b * 512 + tid] = u0;
  }
  __syncthreads();
  for (int h = 0; h < 3; ++h) {
    {
      int m = tid & 127;
      int half = tid >> 7;
      const float* STp = ST + (((size_t)h * B_ + b) * D_ + half * 128) * M_;
      float l = 0.f;
#pragma unroll 16
      for (int d = 0; d < 128; ++d)
        l += us[half * 128 + d] * STp[(size_t)d * M_ + m];
      if (half == 0) lo[m] = l; else loB[m] = l;
    }
    __syncthreads();
    if (h == 2) {
      if (tid < M_) p_ptr[b * M_ + tid] = lo[tid] + loB[tid];
      break;
    }
    if (tid < 64) {
      float l0 = lo[tid] + loB[tid], l1 = lo[tid + 64] + loB[tid + 64];
      float a = fmaxf(l0, l1);
      for (int o = 32; o > 0; o >>= 1) a = fmaxf(a, __shfl_xor(a, o));
      float e0 = expf(l0 - a), e1 = expf(l1 - a);
      float s = e0 + e1;
      for (int o = 32; o > 0; o >>= 1) s += __shfl_xor(s, o);
      pr[tid] = e0 / s;
      pr[tid + 64] = e1 / s;
    }
    __syncthreads();
    {
      const float* Sn = S + (((size_t)(h + 1) * B_ + b) * M_) * D_;
      float o = 0.f;
#pragma unroll 16
      for (int m = 0; m < M_; ++m) o += pr[m] * Sn[(size_t)m * D_ + tid];
      if (h == 0) cat[b * 512 + D_ + tid] = o;
      us[tid] += o;
    }
    __syncthreads();
  }
}

// ---------------- K_pvocab: p_vocab = cat @ W1_w^T + b ----------------------
__global__ __launch_bounds__(256) void k_pvocab(
    const float* __restrict__ cat, const float* __restrict__ W1_w,
    const float* __restrict__ W1_b, float* __restrict__ out) {
  int blk = blockIdx.x, tid = threadIdx.x;
  int row = tid & 63, q = tid >> 6;  // q in 0..3 (k quarter)
  int v = blk * 64 + row;
  __shared__ float cs[B_ * 512];
  __shared__ float ps[3][64][B_];  // quarters 1..3 partials (12 KB)
  for (int i = tid; i < B_ * 512; i += 256) cs[i] = cat[i];
  __syncthreads();
  const float4* wrow = (const float4*)(W1_w + (size_t)v * 512 + q * 128);
  float acc[B_];
#pragma unroll
  for (int b = 0; b < B_; ++b) acc[b] = 0.f;
#pragma unroll 4
  for (int k4 = 0; k4 < 32; ++k4) {
    float4 w = wrow[k4];
#pragma unroll
    for (int b = 0; b < B_; ++b) {
      const float* c = &cs[b * 512 + q * 128 + k4 * 4];
      acc[b] += w.x * c[0] + w.y * c[1] + w.z * c[2] + w.w * c[3];
    }
  }
  if (q > 0) {
#pragma unroll
    for (int b = 0; b < B_; ++b) ps[q - 1][row][b] = acc[b];
  }
  __syncthreads();
  if (q == 0) {
    float bb = W1_b[v];
#pragma unroll
    for (int b = 0; b < B_; ++b)
      out[(size_t)b * VOCAB_ + v] =
          acc[b] + ps[0][row][b] + ps[1][row][b] + ps[2][row][b] + bb;
  }
}

extern "C" void kernel_launch(void* const* d_in, const int* in_sizes, int n_in,
                              void* d_out, int out_size, void* d_ws,
                              size_t ws_size, hipStream_t stream) {
  const int* decoder_input = (const int*)d_in[0];
  const int* story = (const int*)d_in[1];
  const float* hidden = (const float*)d_in[2];
  const int* kb_values = (const int*)d_in[3];
  const int* kb_types = (const int*)d_in[4];
  const float* C = (const float*)d_in[7];
  const float* T_emb = (const float*)d_in[8];
  const float* Wq = (const float*)d_in[9];
  const float* Wk = (const float*)d_in[10];
  const float* Wv = (const float*)d_in[11];
  const float* W1_w = (const float*)d_in[12];
  const float* W1_b = (const float*)d_in[13];
  const float* W_ih = (const float*)d_in[14];
  const float* W_hh = (const float*)d_in[15];
  const float* b_ih = (const float*)d_in[16];
  const float* b_hh = (const float*)d_in[17];

  float* out = (float*)d_out;
  float* p_ptr = out;                          // (16,128)
  float* p_vocab = out + B_ * M_;              // (16,32000)
  float* h_new = out + B_ * M_ + B_ * VOCAB_;  // (16,256)

  // workspace layout (floats). entries aliases into the wtmp tail (dead by
  // k_mid, when ST overwrites); WvT sits past both ST and entries.
  float* ws = (float*)d_ws;
  float* S = ws;                           // 1,572,864
  float* part = S + 3 * B_ * M_ * D_;      // 2,097,152 (B*NT*8ranges*D)
  float* rsum = part + B_ * NT * 8 * D_;   //   262,144
  float* cat = rsum + B_ * NT * D_;        //     8,192
  float* scores = cat + B_ * 512;          //     1,024
  float* gi = scores + B_ * NT;            //    12,288
  float* gh = gi + B_ * 768;               //    12,288
  float* tvec = gh + B_ * 768;             //     4,096
  int* counts = (int*)(tvec + B_ * D_);    //     8,192 ints
  int* qctr = counts + 8192;               //         8 ints (work queues)
  ushort_t* C0h = (ushort_t*)(qctr + 8);   // 8,192,000 ushorts
  float* wtmp = (float*)(C0h + (size_t)VOCAB_ * D_);
  float* W_ihT = wtmp;                        //   196,608
  float* W_hhT = W_ihT + 768 * D_;            //   196,608
  float* TQK = W_hhT + 768 * D_;              //    65,536
  int* entries = (int*)(TQK + D_ * D_);       // 1,572,864 ints (8192*ECAP)
  float* ST = wtmp;                           // alias: 1,572,864 (k_mid+)
  float* WvT = wtmp + (458752 + 1572864);     //    65,536 (past ST & entries)

  hipLaunchKernelGGL(
      k_prep, dim3(NB_S + NB_CONV + 2 * NB_TR + NB_TQK + NB_WVT + NB_BKT),
      dim3(256), 0, stream, story, C, W_ih, W_hh, Wq, Wk, Wv, kb_values,
      kb_types, S, C0h, W_ihT, W_hhT, TQK, WvT, entries, counts, qctr);
  hipLaunchKernelGGL(k_rootsg, dim3(NBG + 7), dim3(512), 0, stream, counts,
                     entries, C0h, T_emb, decoder_input, C, hidden, W_ihT,
                     W_hhT, TQK, b_ih, b_hh, part, gi, gh, tvec, qctr);
  hipLaunchKernelGGL(k_mid, dim3(1024 + 1536), dim3(256), 0, stream, part,
                     tvec, S, scores, ST, rsum);
  hipLaunchKernelGGL(k_chain, dim3(B_), dim3(256), 0, stream, scores, rsum,
                     WvT, gi, gh, hidden, S, ST, h_new, cat, p_ptr);
  hipLaunchKernelGGL(k_pvocab, dim3(VOCAB_ / 64), dim3(256), 0, stream, cat,
                     W1_w, W1_b, p_vocab);
}

// Round 9
// 405.560 us; speedup vs baseline: 1.4995x; 1.1194x over previous
//
#include <hip/hip_runtime.h>
#include <hip/hip_bf16.h>
#include <math.h>

#define B_ 16
#define NT 64
#define LN 256
#define LV 4
#define D_ 256
#define VOCAB_ 32000
#define M_ 128
#define LS 4
#define ECAP 192  // per-(bn,range8) capacity; mean ~131, sigma ~10.7 -> +5.7 sigma

typedef unsigned short ushort_t;
typedef unsigned int uint_t;

__device__ __forceinline__ ushort_t f2bf(float f) {
  uint_t u = __float_as_uint(f);
  uint_t r = u + 0x7FFFu + ((u >> 16) & 1u);
  return (ushort_t)(r >> 16);
}
__device__ __forceinline__ float bflo(uint_t u) {
  return __uint_as_float(u << 16);
}
__device__ __forceinline__ float bfhi(uint_t u) {
  return __uint_as_float(u & 0xFFFF0000u);
}

// ---------------- K_prep: S gather | C0->bf16 | W_ih^T | W_hh^T | TQK | WvT
// | bucketize kb entries by (value-range8, type), zero-padded to x8 ----------
#define NB_S (3 * B_ * M_)  // 6144
#define NB_CONV 2048
#define NB_TR 192   // 768x256 -> 24x8 tiles of 32x32 (per weight)
#define NB_TQK 256
#define NB_WVT 64   // 256x256 -> 8x8 tiles
#define NB_BKT (B_ * NT)  // 1024 bucketing blocks
__global__ __launch_bounds__(256) void k_prep(
    const int* __restrict__ story, const float* __restrict__ C,
    const float* __restrict__ W_ih, const float* __restrict__ W_hh,
    const float* __restrict__ Wq, const float* __restrict__ Wk,
    const float* __restrict__ Wv, const int* __restrict__ kb_values,
    const int* __restrict__ kb_types, float* __restrict__ S,
    ushort_t* __restrict__ C0h, float* __restrict__ W_ihT,
    float* __restrict__ W_hhT, float* __restrict__ TQK,
    float* __restrict__ WvT, int* __restrict__ entries,
    int* __restrict__ counts, int* __restrict__ qctr) {
  __shared__ __align__(16) char praw[7424];
  float* smem = (float*)praw;  // 32*33 floats fit (4224 B)
  int blk = blockIdx.x, tid = threadIdx.x;
  if (blk == 0 && tid < 8) qctr[tid] = 0;  // reset k_rootsg work queues
  if (blk < NB_S) {
    int h = blk / (B_ * M_);
    int bm = blk % (B_ * M_);
    const int* st = story + (size_t)bm * LS;
    const float* Ch = C + (size_t)h * VOCAB_ * D_;
    float s = Ch[(size_t)st[0] * D_ + tid] + Ch[(size_t)st[1] * D_ + tid] +
              Ch[(size_t)st[2] * D_ + tid] + Ch[(size_t)st[3] * D_ + tid];
    S[(size_t)blk * D_ + tid] = s;
  } else if (blk < NB_S + NB_CONV) {
    int n4 = VOCAB_ * D_ / 4;
    for (int i = (blk - NB_S) * 256 + tid; i < n4; i += NB_CONV * 256) {
      float4 f = ((const float4*)C)[i];
      uint2 packed;
      packed.x = (uint_t)f2bf(f.x) | ((uint_t)f2bf(f.y) << 16);
      packed.y = (uint_t)f2bf(f.z) | ((uint_t)f2bf(f.w) << 16);
      ((uint2*)C0h)[i] = packed;
    }
  } else if (blk < NB_S + NB_CONV + 2 * NB_TR) {
    int t = blk - (NB_S + NB_CONV);
    const float* W = W_ih;
    float* WT = W_ihT;
    if (t >= NB_TR) { t -= NB_TR; W = W_hh; WT = W_hhT; }
    const int R = 768;
    int tr = t % (R / 32), tc = t / (R / 32);
    int tx = tid & 31, ty = tid >> 5;
#pragma unroll
    for (int k = 0; k < 4; ++k)
      smem[(ty + 8 * k) * 33 + tx] =
          W[(size_t)(tr * 32 + ty + 8 * k) * D_ + tc * 32 + tx];
    __syncthreads();
#pragma unroll
    for (int k = 0; k < 4; ++k)
      WT[(size_t)(tc * 32 + ty + 8 * k) * R + tr * 32 + tx] =
          smem[tx * 33 + ty + 8 * k];
  } else if (blk < NB_S + NB_CONV + 2 * NB_TR + NB_TQK) {
    // TQK[j,i] = sum_k Wq[k,j] * Wk[k,i]
    int j = blk - (NB_S + NB_CONV + 2 * NB_TR);
    smem[tid] = Wq[(size_t)tid * D_ + j];
    __syncthreads();
    float acc = 0.f;
#pragma unroll 8
    for (int k = 0; k < D_; ++k) acc += smem[k] * Wk[(size_t)k * D_ + tid];
    TQK[(size_t)j * D_ + tid] = acc;
  } else if (blk < NB_S + NB_CONV + 2 * NB_TR + NB_TQK + NB_WVT) {
    // WvT[j,r] = Wv[r,j]
    int t = blk - (NB_S + NB_CONV + 2 * NB_TR + NB_TQK);
    int tr = t & 7, tc = t >> 3;
    int tx = tid & 31, ty = tid >> 5;
#pragma unroll
    for (int k = 0; k < 4; ++k)
      smem[(ty + 8 * k) * 33 + tx] =
          Wv[(size_t)(tr * 32 + ty + 8 * k) * D_ + tc * 32 + tx];
    __syncthreads();
#pragma unroll
    for (int k = 0; k < 4; ++k)
      WvT[(size_t)(tc * 32 + ty + 8 * k) * D_ + tr * 32 + tx] =
          smem[tx * 33 + ty + 8 * k];
  } else {
    // ---- bucketize: counting-sort (value,type) pairs by (range8,type) ------
    int bn = blk - (NB_S + NB_CONV + 2 * NB_TR + NB_TQK + NB_WVT);
    int* sval = (int*)praw;     // 1024 ints (4 KB)
    int* stype = sval + 1024;   //  256 ints (1 KB)
    int* sbin = stype + 256;    //  512 ints (2 KB): histogram->prefix->ctr
    int* srng = sbin + 512;     //    8 ints: range starts
    int* scnt = srng + 8;       //    8 ints: capped counts
    const int* vp = kb_values + (size_t)bn * LN * LV;
    for (int i = tid; i < LN * LV; i += 256) sval[i] = vp[i];
    stype[tid] = kb_types[(size_t)bn * LN + tid];
    sbin[tid] = 0;
    sbin[256 + tid] = 0;
    __syncthreads();
    int ty = stype[tid];
    int vv[4];
#pragma unroll
    for (int j = 0; j < 4; ++j) {
      vv[j] = sval[tid * 4 + j];
      atomicAdd(&sbin[((vv[j] >> 12) << 6) | ty], 1);
    }
    __syncthreads();
    if (tid < 64) {  // wave 0: exclusive prefix over 512 bins
      int run = 0;
#pragma unroll
      for (int c = 0; c < 8; ++c) {
        int x = sbin[c * 64 + tid];
        int orig = x;
        for (int o = 1; o < 64; o <<= 1) {
          int y = __shfl_up(x, o);
          if ((int)tid >= o) x += y;
        }
        sbin[c * 64 + tid] = x - orig + run;  // exclusive global prefix
        run += __shfl(x, 63);                 // chunk total
      }
    }
    __syncthreads();
    if (tid < 8) {
      srng[tid] = sbin[tid << 6];
      int e = (tid == 7) ? (LN * LV) : sbin[(tid + 1) << 6];
      int cv = min(e - sbin[tid << 6], ECAP);
      counts[bn * 8 + tid] = cv;
      scnt[tid] = cv;
    }
    __syncthreads();
#pragma unroll
    for (int j = 0; j < 4; ++j) {
      int v = vv[j];
      int r = v >> 12;
      int pos = atomicAdd(&sbin[(r << 6) | ty], 1) - srng[r];
      if (pos < ECAP)
        entries[(size_t)(bn * 8 + r) * ECAP + pos] = v | (ty << 16);
    }
    __syncthreads();
    // zero-pad each bucket to x8 (value 0 -> C0 row 0 == 0, type 0 ->
    // T_emb row 0 == 0 -> exact zero contribution)
    if (tid < 8) {
      int cv = scnt[tid];
      int cp = (cv + 7) & ~7;
      for (int p = cv; p < cp; ++p)
        entries[(size_t)(bn * 8 + tid) * ECAP + p] = 0;
    }
  }
}

// ---------------- K_rootsg: paired-row 16B/lane gather + gates --------------
// r4 vs r8 isolated the invariant: time scales with VECTOR-LOAD INSTRUCTION
// count (~42 cyc/instr/CU; bytes and cache lines identical). So: 2 entries
// per load -- lanes 0-31 read entry k's full 512 B row (uint4 = 16 B/lane),
// lanes 32-63 entry k+1 -> 0.53 M loads (4x fewer than r8). r5's two poisons
// removed: no min-waves bound (keeps ~80 VGPR), and T_emb LDS stored PERMUTED
// ([32 even f4][32 odd f4] per type) so each lane's two ds_read_b128 are
// stride-16B contiguous -> conflict-free (r5's stride-32 was 8-way, 4.25M).
// Cross-half combine: 8x shfl_xor(32) once per bucket. 8-range XCC claim
// kept. LDS 70 KB -> 2 blocks/CU x 8 waves = 16 waves/CU.
#define NBG 1024
#define NRANGE 8
#define UNITS_PER_RANGE 128  // 1024 bn / 8 bn-per-unit
__global__ __launch_bounds__(512) void k_rootsg(
    const int* __restrict__ counts, const int* __restrict__ entries,
    const ushort_t* __restrict__ C0h, const float* __restrict__ T_emb,
    const int* __restrict__ dec, const float* __restrict__ C0,
    const float* __restrict__ hidden, const float* __restrict__ W_ihT,
    const float* __restrict__ W_hhT, const float* __restrict__ TQK,
    const float* __restrict__ b_ih, const float* __restrict__ b_hh,
    float* __restrict__ part, float* __restrict__ gi, float* __restrict__ gh,
    float* __restrict__ tvec, int* __restrict__ qctr) {
  __shared__ __align__(16) char smem_raw[65536 + 6144 + 16];
  int blk = blockIdx.x, tid = threadIdx.x;
  if (blk < NBG) {
    float4* t4s = (float4*)smem_raw;                // permuted [64][64] f4
    int* ent_all = (int*)(smem_raw + 65536);        // [8][192]
    int* sunit = (int*)(smem_raw + 65536 + 6144);   // claim broadcast
    if (tid == 0) {
      int xcd = __builtin_amdgcn_s_getreg(6164) & 7;  // hwreg(XCC_ID=20,0,4)
      int unit = -1;
      for (int a = 0; a < NRANGE && unit < 0; ++a) {
        int rr = (xcd + a) & 7;
        int u = atomicAdd(&qctr[rr], 1);
        if (u < UNITS_PER_RANGE) unit = (u << 3) | rr;
      }
      sunit[0] = unit;
    }
    // stage T_emb permuted: dest (ty, j): j<32 -> float4 of cols 8j..8j+3
    // (even f4 of lane j); j>=32 -> cols 8(j-32)+4..+7 (odd f4 of lane j-32)
    const float4* Tg = (const float4*)T_emb;
    for (int i = tid; i < 64 * 64; i += 512) {
      int ty = i >> 6, j = i & 63;
      t4s[i] = Tg[ty * 64 + 2 * (j & 31) + (j >> 5)];
    }
    __syncthreads();
    int unit = sunit[0];
    if (unit < 0) return;  // all units already claimed (safety)
    int rr = unit & 7, u = unit >> 3;
    int wid = tid >> 6, lane = tid & 63;
    int l31 = lane & 31;
    int half = lane >> 5;
    int bn = u * 8 + wid;
    int bucket = bn * 8 + rr;
    int cnt = counts[bucket];
    int cnt2 = (cnt + 1) & ~1;  // pairs; zero-pad to x8 covers this
    const int* ge = entries + (size_t)bucket * ECAP;
    int* ent = ent_all + wid * ECAP;
    for (int i = lane; i < cnt2; i += 64) ent[i] = ge[i];
    const ushort_t* C0base = C0h + 8 * l31;  // lane's 16 B column window
    float a0 = 0.f, a1 = 0.f, a2 = 0.f, a3 = 0.f;
    float a4 = 0.f, a5 = 0.f, a6 = 0.f, a7 = 0.f;
#pragma unroll 2
    for (int k = 0; k < cnt2; k += 2) {
      int e = ent[k + half];  // 2 addrs/wave -> broadcast, free
      uint4 uu = *(const uint4*)(C0base + ((size_t)(e & 0xFFFF) << 8));
      int ty = e >> 16;
      float4 ta = t4s[(ty << 6) | l31];       // cols 8*l31..+3
      float4 tb = t4s[(ty << 6) | 32 | l31];  // cols 8*l31+4..+7
      a0 += ta.x * bflo(uu.x);
      a1 += ta.y * bfhi(uu.x);
      a2 += ta.z * bflo(uu.y);
      a3 += ta.w * bfhi(uu.y);
      a4 += tb.x * bflo(uu.z);
      a5 += tb.y * bfhi(uu.z);
      a6 += tb.z * bflo(uu.w);
      a7 += tb.w * bfhi(uu.w);
    }
    // combine halves: lane i (+) lane i+32 hold same cols, disjoint entries
    a0 += __shfl_xor(a0, 32);
    a1 += __shfl_xor(a1, 32);
    a2 += __shfl_xor(a2, 32);
    a3 += __shfl_xor(a3, 32);
    a4 += __shfl_xor(a4, 32);
    a5 += __shfl_xor(a5, 32);
    a6 += __shfl_xor(a6, 32);
    a7 += __shfl_xor(a7, 32);
    if (half == 0) {
      float4 r0v, r1v;
      r0v.x = a0; r0v.y = a1; r0v.z = a2; r0v.w = a3;
      r1v.x = a4; r1v.y = a5; r1v.z = a6; r1v.w = a7;
      float4* pp = (float4*)(part + (size_t)bucket * D_ + 8 * l31);
      pp[0] = r0v;
      pp[1] = r1v;
    }
  } else {
    int g = blk - NBG;  // 0..2: gi, 3..5: gh, 6: tvec
    float* xs = (float*)smem_raw;  // [16][64] = 4 KB, chunked over j
    float acc[B_];
    int i = (g < 3 ? g : g - 3) * 256 + tid;  // valid for tid<256
    if (g < 3) {
      float bias = (tid < 256) ? b_ih[i] : 0.f;
#pragma unroll
      for (int b = 0; b < B_; ++b) acc[b] = bias;
      for (int c = 0; c < 4; ++c) {
        __syncthreads();
        for (int idx = tid; idx < B_ * 64; idx += 512) {
          int b = idx >> 6, jj = idx & 63;
          xs[idx] = C0[(size_t)dec[b] * D_ + c * 64 + jj];
        }
        __syncthreads();
        if (tid < 256) {
#pragma unroll 4
          for (int jj = 0; jj < 64; ++jj) {
            float w = W_ihT[(size_t)(c * 64 + jj) * 768 + i];
#pragma unroll
            for (int b = 0; b < B_; ++b) acc[b] += xs[b * 64 + jj] * w;
          }
        }
      }
      if (tid < 256) {
#pragma unroll
        for (int b = 0; b < B_; ++b) gi[(size_t)b * 768 + i] = acc[b];
      }
    } else if (g < 6) {
      float bias = (tid < 256) ? b_hh[i] : 0.f;
#pragma unroll
      for (int b = 0; b < B_; ++b) acc[b] = bias;
      for (int c = 0; c < 4; ++c) {
        __syncthreads();
        for (int idx = tid; idx < B_ * 64; idx += 512) {
          int b = idx >> 6, jj = idx & 63;
          xs[idx] = hidden[b * D_ + c * 64 + jj];
        }
        __syncthreads();
        if (tid < 256) {
#pragma unroll 4
          for (int jj = 0; jj < 64; ++jj) {
            float w = W_hhT[(size_t)(c * 64 + jj) * 768 + i];
#pragma unroll
            for (int b = 0; b < B_; ++b) acc[b] += xs[b * 64 + jj] * w;
          }
        }
      }
      if (tid < 256) {
#pragma unroll
        for (int b = 0; b < B_; ++b) gh[(size_t)b * 768 + i] = acc[b];
      }
    } else {
#pragma unroll
      for (int b = 0; b < B_; ++b) acc[b] = 0.f;
      for (int c = 0; c < 4; ++c) {
        __syncthreads();
        for (int idx = tid; idx < B_ * 64; idx += 512) {
          int b = idx >> 6, jj = idx & 63;
          xs[idx] = hidden[b * D_ + c * 64 + jj];
        }
        __syncthreads();
        if (tid < 256) {
#pragma unroll 4
          for (int jj = 0; jj < 64; ++jj) {
            float w = TQK[(size_t)(c * 64 + jj) * D_ + tid];
#pragma unroll
            for (int b = 0; b < B_; ++b) acc[b] += xs[b * 64 + jj] * w;
          }
        }
      }
      if (tid < 256) {
#pragma unroll
        for (int b = 0; b < B_; ++b) tvec[b * D_ + tid] = acc[b];
      }
    }
  }
}

// ---------------- K_mid: scores + rsum (1024 blocks) + S transpose (1536) ---
__global__ __launch_bounds__(256) void k_mid(
    const float* __restrict__ part, const float* __restrict__ tvec,
    const float* __restrict__ S, float* __restrict__ scores,
    float* __restrict__ ST, float* __restrict__ rsum) {
  int blk = blockIdx.x, tid = threadIdx.x;
  if (blk < 1024) {
    int b = blk >> 6;
    const float* p = part + (size_t)blk * 8 * D_;
    float rv = 0.f;
#pragma unroll
    for (int r = 0; r < 8; ++r) rv += p[r * D_ + tid];
    rsum[(size_t)blk * D_ + tid] = rv;
    float sc = rv * tvec[b * D_ + tid];
    float sm = rv;
    __shared__ float red[8];
    int lane = tid & 63, wave = tid >> 6;
    for (int o = 32; o > 0; o >>= 1) {
      sc += __shfl_xor(sc, o);
      sm += __shfl_xor(sm, o);
    }
    if (lane == 0) { red[wave] = sc; red[4 + wave] = sm; }
    __syncthreads();
    if (tid == 0) {
      float SC = red[0] + red[1] + red[2] + red[3];
      float SM = red[4] + red[5] + red[6] + red[7];
      scores[blk] = (SM == 0.0f) ? SC - 1000000000.0f : SC;
    }
  } else {
    // ST[hb][d][m] = S[hb][m][d]
    int t = blk - 1024;
    int hb = t >> 5;
    int tile = t & 31;
    int tm = tile & 3, td = tile >> 2;
    int tx = tid & 31, ty = tid >> 5;
    __shared__ float sm2[32 * 33];
    const float* Sp = S + (size_t)hb * M_ * D_;
    float* STp = ST + (size_t)hb * D_ * M_;
#pragma unroll
    for (int k = 0; k < 4; ++k)
      sm2[(ty + 8 * k) * 33 + tx] =
          Sp[(size_t)(tm * 32 + ty + 8 * k) * D_ + td * 32 + tx];
    __syncthreads();
#pragma unroll
    for (int k = 0; k < 4; ++k)
      STp[(size_t)(td * 32 + ty + 8 * k) * M_ + tm * 32 + tx] =
          sm2[tx * 33 + ty + 8 * k];
  }
}

// ---------------- K_chain: softmax/rbar/feat/GRU/hops (grid=16) -------------
__global__ __launch_bounds__(256) void k_chain(
    const float* __restrict__ scores, const float* __restrict__ rsum,
    const float* __restrict__ WvT, const float* __restrict__ gi,
    const float* __restrict__ gh, const float* __restrict__ hidden,
    const float* __restrict__ S, const float* __restrict__ ST,
    float* __restrict__ h_new_out, float* __restrict__ cat,
    float* __restrict__ p_ptr) {
  int b = blockIdx.x, tid = threadIdx.x;
  __shared__ float wsh[NT], rs[D_], us[D_], lo[M_], loB[M_], pr[M_];
  if (tid < NT) {
    float s = scores[b * NT + tid];
    float m = s;
    for (int o = 32; o > 0; o >>= 1) m = fmaxf(m, __shfl_xor(m, o));
    float e = expf(s - m);
    float sum = e;
    for (int o = 32; o > 0; o >>= 1) sum += __shfl_xor(sum, o);
    wsh[tid] = e / sum;
  }
  __syncthreads();
  float rb = 0.f;
#pragma unroll 16
  for (int n = 0; n < NT; ++n)
    rb += wsh[n] * rsum[(size_t)(b * NT + n) * D_ + tid];
  rs[tid] = rb;
  __syncthreads();
  float feat = 0.f;
#pragma unroll 16
  for (int j = 0; j < D_; ++j) feat += rs[j] * WvT[(size_t)j * D_ + tid];
  {
    float i_r = gi[(size_t)b * 768 + tid];
    float i_z = gi[(size_t)b * 768 + 256 + tid];
    float i_n = gi[(size_t)b * 768 + 512 + tid];
    float h_r = gh[(size_t)b * 768 + tid];
    float h_z = gh[(size_t)b * 768 + 256 + tid];
    float h_n = gh[(size_t)b * 768 + 512 + tid];
    float h = hidden[b * D_ + tid];
    float r = 1.f / (1.f + expf(-(i_r + h_r)));
    float z = 1.f / (1.f + expf(-(i_z + h_z)));
    float nn = tanhf(i_n + r * h_n);
    float hn = (1.f - z) * nn + z * h;
    h_new_out[b * D_ + tid] = hn;
    float u0 = hn + feat;
    us[tid] = u0;
    cat[b * 512 + tid] = u0;
  }
  __syncthreads();
  for (int h = 0; h < 3; ++h) {
    {
      int m = tid & 127;
      int half = tid >> 7;
      const float* STp = ST + (((size_t)h * B_ + b) * D_ + half * 128) * M_;
      float l = 0.f;
#pragma unroll 16
      for (int d = 0; d < 128; ++d)
        l += us[half * 128 + d] * STp[(size_t)d * M_ + m];
      if (half == 0) lo[m] = l; else loB[m] = l;
    }
    __syncthreads();
    if (h == 2) {
      if (tid < M_) p_ptr[b * M_ + tid] = lo[tid] + loB[tid];
      break;
    }
    if (tid < 64) {
      float l0 = lo[tid] + loB[tid], l1 = lo[tid + 64] + loB[tid + 64];
      float a = fmaxf(l0, l1);
      for (int o = 32; o > 0; o >>= 1) a = fmaxf(a, __shfl_xor(a, o));
      float e0 = expf(l0 - a), e1 = expf(l1 - a);
      float s = e0 + e1;
      for (int o = 32; o > 0; o >>= 1) s += __shfl_xor(s, o);
      pr[tid] = e0 / s;
      pr[tid + 64] = e1 / s;
    }
    __syncthreads();
    {
      const float* Sn = S + (((size_t)(h + 1) * B_ + b) * M_) * D_;
      float o = 0.f;
#pragma unroll 16
      for (int m = 0; m < M_; ++m) o += pr[m] * Sn[(size_t)m * D_ + tid];
      if (h == 0) cat[b * 512 + D_ + tid] = o;
      us[tid] += o;
    }
    __syncthreads();
  }
}

// ---------------- K_pvocab: p_vocab = cat @ W1_w^T + b ----------------------
__global__ __launch_bounds__(256) void k_pvocab(
    const float* __restrict__ cat, const float* __restrict__ W1_w,
    const float* __restrict__ W1_b, float* __restrict__ out) {
  int blk = blockIdx.x, tid = threadIdx.x;
  int row = tid & 63, q = tid >> 6;  // q in 0..3 (k quarter)
  int v = blk * 64 + row;
  __shared__ float cs[B_ * 512];
  __shared__ float ps[3][64][B_];  // quarters 1..3 partials (12 KB)
  for (int i = tid; i < B_ * 512; i += 256) cs[i] = cat[i];
  __syncthreads();
  const float4* wrow = (const float4*)(W1_w + (size_t)v * 512 + q * 128);
  float acc[B_];
#pragma unroll
  for (int b = 0; b < B_; ++b) acc[b] = 0.f;
#pragma unroll 4
  for (int k4 = 0; k4 < 32; ++k4) {
    float4 w = wrow[k4];
#pragma unroll
    for (int b = 0; b < B_; ++b) {
      const float* c = &cs[b * 512 + q * 128 + k4 * 4];
      acc[b] += w.x * c[0] + w.y * c[1] + w.z * c[2] + w.w * c[3];
    }
  }
  if (q > 0) {
#pragma unroll
    for (int b = 0; b < B_; ++b) ps[q - 1][row][b] = acc[b];
  }
  __syncthreads();
  if (q == 0) {
    float bb = W1_b[v];
#pragma unroll
    for (int b = 0; b < B_; ++b)
      out[(size_t)b * VOCAB_ + v] =
          acc[b] + ps[0][row][b] + ps[1][row][b] + ps[2][row][b] + bb;
  }
}

extern "C" void kernel_launch(void* const* d_in, const int* in_sizes, int n_in,
                              void* d_out, int out_size, void* d_ws,
                              size_t ws_size, hipStream_t stream) {
  const int* decoder_input = (const int*)d_in[0];
  const int* story = (const int*)d_in[1];
  const float* hidden = (const float*)d_in[2];
  const int* kb_values = (const int*)d_in[3];
  const int* kb_types = (const int*)d_in[4];
  const float* C = (const float*)d_in[7];
  const float* T_emb = (const float*)d_in[8];
  const float* Wq = (const float*)d_in[9];
  const float* Wk = (const float*)d_in[10];
  const float* Wv = (const float*)d_in[11];
  const float* W1_w = (const float*)d_in[12];
  const float* W1_b = (const float*)d_in[13];
  const float* W_ih = (const float*)d_in[14];
  const float* W_hh = (const float*)d_in[15];
  const float* b_ih = (const float*)d_in[16];
  const float* b_hh = (const float*)d_in[17];

  float* out = (float*)d_out;
  float* p_ptr = out;                          // (16,128)
  float* p_vocab = out + B_ * M_;              // (16,32000)
  float* h_new = out + B_ * M_ + B_ * VOCAB_;  // (16,256)

  // workspace layout (floats). entries aliases into the wtmp tail (dead by
  // k_mid, when ST overwrites); WvT sits past both ST and entries.
  float* ws = (float*)d_ws;
  float* S = ws;                           // 1,572,864
  float* part = S + 3 * B_ * M_ * D_;      // 2,097,152 (B*NT*8ranges*D)
  float* rsum = part + B_ * NT * 8 * D_;   //   262,144
  float* cat = rsum + B_ * NT * D_;        //     8,192
  float* scores = cat + B_ * 512;          //     1,024
  float* gi = scores + B_ * NT;            //    12,288
  float* gh = gi + B_ * 768;               //    12,288
  float* tvec = gh + B_ * 768;             //     4,096
  int* counts = (int*)(tvec + B_ * D_);    //     8,192 ints
  int* qctr = counts + 8192;               //         8 ints (work queues)
  ushort_t* C0h = (ushort_t*)(qctr + 8);   // 8,192,000 ushorts
  float* wtmp = (float*)(C0h + (size_t)VOCAB_ * D_);
  float* W_ihT = wtmp;                        //   196,608
  float* W_hhT = W_ihT + 768 * D_;            //   196,608
  float* TQK = W_hhT + 768 * D_;              //    65,536
  int* entries = (int*)(TQK + D_ * D_);       // 1,572,864 ints (8192*ECAP)
  float* ST = wtmp;                           // alias: 1,572,864 (k_mid+)
  float* WvT = wtmp + (458752 + 1572864);     //    65,536 (past ST & entries)

  hipLaunchKernelGGL(
      k_prep, dim3(NB_S + NB_CONV + 2 * NB_TR + NB_TQK + NB_WVT + NB_BKT),
      dim3(256), 0, stream, story, C, W_ih, W_hh, Wq, Wk, Wv, kb_values,
      kb_types, S, C0h, W_ihT, W_hhT, TQK, WvT, entries, counts, qctr);
  hipLaunchKernelGGL(k_rootsg, dim3(NBG + 7), dim3(512), 0, stream, counts,
                     entries, C0h, T_emb, decoder_input, C, hidden, W_ihT,
                     W_hhT, TQK, b_ih, b_hh, part, gi, gh, tvec, qctr);
  hipLaunchKernelGGL(k_mid, dim3(1024 + 1536), dim3(256), 0, stream, part,
                     tvec, S, scores, ST, rsum);
  hipLaunchKernelGGL(k_chain, dim3(B_), dim3(256), 0, stream, scores, rsum,
                     WvT, gi, gh, hidden, S, ST, h_new, cat, p_ptr);
  hipLaunchKernelGGL(k_pvocab, dim3(VOCAB_ / 64), dim3(256), 0, stream, cat,
                     W1_w, W1_b, p_vocab);
}